// Round 14
// baseline (3508.232 us; speedup 1.0000x reference)
//
#include <hip/hip_runtime.h>
#include <hip/hip_bf16.h>
#include <stdint.h>

// Problem constants
#define Bsz 512
#define Tsz 512
#define Fsz 16
#define Hsz 256
#define HORZ 24

// 3 layers x 8 gate-slices x 8 batch-tiles = 192 blocks; batch HALVES time-sliced
#define NG 8
#define NBT 8
#define BT 64
#define HR 32           // rows per half
#define USL 32          // hidden units per slice (128 gate cols)
#define PD 8            // h slot depth (power of 2)
#define HBUF_ELEMS ((size_t)3*PD*Bsz*Hsz)
#define NFLAGS (3*NG*NBT)
#define SMEM_B (84*1024)            // pad -> exactly 1 block/CU

#define POISON   0x7FC07FC0u
#define POISON64 0x7FC07FC07FC07FC0ull

typedef float  f32x4  __attribute__((ext_vector_type(4)));
typedef __bf16 bf16x8 __attribute__((ext_vector_type(8)));
typedef uint32_t u32x4 __attribute__((ext_vector_type(4)));

__device__ __forceinline__ float sigm(float v){ return 1.f/(1.f+__expf(-v)); }

// ---- verified sc01 (IC-coherent) helpers; only vmcnt(0) drains anywhere ----
__device__ __forceinline__ bf16x8 ld_sc01_b128(const void* p){
  bf16x8 r;
  asm volatile("global_load_dwordx4 %0, %1, off sc0 sc1" : "=&v"(r) : "v"(p) : "memory");
  return r;
}
__device__ __forceinline__ uint32_t ld_b32_async(const void* p){   // plain cached (x)
  uint32_t r;
  asm volatile("global_load_dword %0, %1, off" : "=&v"(r) : "v"(p) : "memory");
  return r;
}
__device__ __forceinline__ void st_sc01_b64(void* p, uint64_t v){
  asm volatile("global_store_dwordx2 %0, %1, off sc0 sc1" :: "v"(p), "v"(v) : "memory");
}
__device__ __forceinline__ void st_sc01_b32(void* p, uint32_t v){
  asm volatile("global_store_dword %0, %1, off sc0 sc1" :: "v"(p), "v"(v) : "memory");
}
__device__ __forceinline__ uint32_t ld_sc01_b32(const void* p){
  uint32_t r;
  asm volatile("global_load_dword %0, %1, off sc0 sc1\n\ts_waitcnt vmcnt(0)"
    : "=&v"(r) : "v"(p) : "memory");
  return r;
}
__device__ __forceinline__ void wait_flag(const unsigned int* fp, int target){
  int guard = 0;
  while ((int)ld_sc01_b32(fp) < target){
    __builtin_amdgcn_s_sleep(1);
    if (++guard > (1<<18)) break;   // fail-fast
  }
}
__device__ __forceinline__ bool pf_ok2(const bf16x8* v){
  u32x4 a = __builtin_bit_cast(u32x4, v[0]);
  u32x4 b = __builtin_bit_cast(u32x4, v[1]);
  return (a[0]!=POISON) & (a[2]!=POISON) & (b[0]!=POISON) & (b[2]!=POISON);
}
__device__ __forceinline__ void poll_load2(bf16x8* d, const __bf16* src){
  int guard = 0;
  for(;;){
    d[0] = ld_sc01_b128(src);
    d[1] = ld_sc01_b128(src + 8);
    asm volatile("s_waitcnt vmcnt(0)" ::: "memory");
    __builtin_amdgcn_sched_barrier(0);
    if (pf_ok2(d)) break;
    __builtin_amdgcn_s_sleep(1);
    if (++guard > (1<<16)) break;   // fail-fast
  }
}

// One half-interval: drain/check/stage X(t) -> MFMA+epilogue -> store+poison ->
// issue prefetches for the other half (its step TY). All drains vmcnt(0).
#define HALF_ITER(T, TY, RB, RBN, HRCX, AINX, HTX, CSTX, HRV, HIV, XV, HRVN, HIVN, XVN) \
  {                                                                                     \
    if ((T) > 0){                                                                       \
      asm volatile("s_waitcnt vmcnt(0)" ::: "memory");                                  \
      __builtin_amdgcn_sched_barrier(0);                                                \
      if (!pf_ok2(HRV))                                                                 \
        poll_load2(HRV, slotp(l,(T)-1) + (size_t)(b0+(RB)+sr)*Hsz + sq*16);             \
      *(bf16x8*)((HRCX) + sr*512 + ((sq*32)    ^ skey)) = (HRV)[0];                     \
      *(bf16x8*)((HRCX) + sr*512 + ((sq*32+16) ^ skey)) = (HRV)[1];                     \
      if constexpr (L0){                                                                \
        *(__bf16*)((AINX) + sr*64 + sq*2) = (__bf16)__uint_as_float(XV);                \
      } else {                                                                          \
        if (!pf_ok2(HIV))                                                               \
          poll_load2(HIV, slotp(l-1,(T)) + (size_t)(b0+(RB)+sr)*Hsz + sq*16);           \
        *(bf16x8*)((AINX) + sr*512 + ((sq*32)    ^ skey)) = (HIV)[0];                   \
        *(bf16x8*)((AINX) + sr*512 + ((sq*32+16) ^ skey)) = (HIV)[1];                   \
      }                                                                                 \
    }                                                                                   \
    __syncthreads();                                                                    \
    f32x4 acc0, acc1;                                                                   \
    acc0[0]=0.f;acc0[1]=0.f;acc0[2]=0.f;acc0[3]=0.f;                                    \
    acc1[0]=0.f;acc1[1]=0.f;acc1[2]=0.f;acc1[3]=0.f;                                    \
    _Pragma("unroll")                                                                   \
    for (int c=0;c<NC;++c){                                                             \
      bf16x8 a0, a1;                                                                    \
      if constexpr (L0){                                                                \
        if (c==0){ a0 = *(const bf16x8*)((AINX) + r0*64 + kq16);                        \
                   a1 = *(const bf16x8*)((AINX) + r1*64 + kq16); }                      \
        else { int off = (((c-1)*64) + kq16) ^ akey;                                    \
               a0 = *(const bf16x8*)((HRCX) + r0*512 + off);                            \
               a1 = *(const bf16x8*)((HRCX) + r1*512 + off); }                          \
      } else {                                                                          \
        const char* bse = (c<8) ? (AINX) : (HRCX);                                     \
        int cc = (c<8) ? c : c-8;                                                       \
        int off = ((cc*64) + kq16) ^ akey;                                              \
        a0 = *(const bf16x8*)(bse + r0*512 + off);                                      \
        a1 = *(const bf16x8*)(bse + r1*512 + off);                                      \
      }                                                                                 \
      acc0 = __builtin_amdgcn_mfma_f32_16x16x32_bf16(a0, w[c], acc0, 0,0,0);            \
      acc1 = __builtin_amdgcn_mfma_f32_16x16x32_bf16(a1, w[c], acc1, 0,0,0);            \
    }                                                                                   \
    _Pragma("unroll")                                                                   \
    for (int mt=0; mt<2; ++mt){                                                         \
      _Pragma("unroll")                                                                 \
      for (int rr=0; rr<4; ++rr){                                                       \
        float v  = (mt ? acc1[rr] : acc0[rr]) + bias;                                   \
        float vv = q2 ? 2.f*v : v;                                                      \
        float sg = sigm(vv);                                                            \
        float act = q2 ? (2.f*sg - 1.f) : sg;                                           \
        float a1f = __shfl_xor(act,1,64);                                               \
        float a2f = __shfl_xor(act,2,64);                                               \
        float a3f = __shfl_xor(act,3,64);                                               \
        if (gate==0){                                                                   \
          float cn = a1f*(CSTX)[mt*4+rr] + act*a2f;                                     \
          (CSTX)[mt*4+rr] = cn;                                                         \
          float hv = a3f*(2.f*sigm(2.f*cn) - 1.f);                                      \
          int rh = mt*16 + kq*4 + rr;                                                   \
          *(__bf16*)((HTX) + rh*64 + unit*2) = (__bf16)hv;                              \
        }                                                                               \
      }                                                                                 \
    }                                                                                   \
    __syncthreads();                                                                    \
    if (tid < 256){                                                                     \
      int row = tid>>3, q = tid&7;                                                      \
      uint64_t v = *(const uint64_t*)((HTX) + row*64 + q*8);                            \
      st_sc01_b64(slotp(l,(T))   + (size_t)(b0+(RB)+row)*Hsz + g*USL + q*4, v);         \
      st_sc01_b64(slotp(l,(T)+1) + (size_t)(b0+(RB)+row)*Hsz + g*USL + q*4, POISON64);  \
    }                                                                                   \
    if ((TY) >= 1 && (TY) < Tsz){                                                       \
      const __bf16* pa = slotp(l,(TY)-1) + (size_t)(b0+(RBN)+sr)*Hsz + sq*16;           \
      (HRVN)[0] = ld_sc01_b128(pa);                                                     \
      (HRVN)[1] = ld_sc01_b128(pa + 8);                                                 \
      if constexpr (L0){                                                                \
        XVN = ld_b32_async(xin + ((size_t)(b0+(RBN)+sr)*Tsz + (TY))*Fsz + sq);          \
      } else {                                                                          \
        const __bf16* pb = slotp(l-1,(TY)) + (size_t)(b0+(RBN)+sr)*Hsz + sq*16;         \
        (HIVN)[0] = ld_sc01_b128(pb);                                                   \
        (HIVN)[1] = ld_sc01_b128(pb + 8);                                               \
      }                                                                                 \
    }                                                                                   \
  }

template<bool L0>
__device__ __forceinline__ void lstm_body(
    int l, int g, int nb, int tid,
    const float* __restrict__ xin,
    const float* __restrict__ Wih0,
    const float* __restrict__ Wih12,
    const float* __restrict__ Whh,
    const float* __restrict__ bih,
    const float* __restrict__ bhh,
    __bf16* __restrict__ hb,
    unsigned int* __restrict__ flags,
    char* smem)
{
  // LDS layout: hrc0 @0 (16K), hrc1 @16K, ain0 @32K, ain1 @(32K+asz), ht0/ht1
  constexpr int ASZ = L0 ? (HR*64) : (HR*512);
  char* hrc0 = smem;
  char* hrc1 = smem + HR*512;
  char* ain0 = smem + 2*HR*512;
  char* ain1 = ain0 + ASZ;
  char* ht0  = ain1 + ASZ;
  char* ht1  = ht0 + HR*64;

  const int lane = tid & 63;
  const int wid  = tid >> 6;                  // 8 waves x 16 cols
  const int b0   = nb * BT;
  const int colL = wid*16 + (lane & 15);      // gate col 0..127
  const int kq   = lane >> 4;                 // 0..3
  const int kq16 = kq * 16;
  const int gate = colL & 3;
  const int unit = colL >> 2;                 // 0..31
  const int R    = gate*Hsz + g*USL + unit;
  const float bias = bih[l*4*Hsz + R] + bhh[l*4*Hsz + R];
  const bool q2 = (gate == 2);
  const int r0 = lane & 15, r1 = 16 + (lane & 15);
  const int akey = (lane & 7) << 4;           // A-read XOR key (r0&7 == r1&7)

  // staging: 16 threads per row, 32B each
  const int sr = tid >> 4, sq = tid & 15;
  const int skey = (sr & 7) << 4;

  // ---- one-time: W -> registers (16x16x32 B-frag: col=lane&15, k=kq*8+j) ----
  constexpr int NC = L0 ? 9 : 16;             // K chunks of 32
  const int kg8 = kq * 8;
  bf16x8 w[NC];
  {
    const float* recB = Whh + ((size_t)l*4*Hsz + R)*Hsz;
    #pragma unroll
    for (int c=0;c<NC;++c){
      bf16x8 t;
      if constexpr (L0){
        if (c==0){
          if (kg8 < Fsz){
            const float* p = Wih0 + (size_t)R*Fsz + kg8;
            #pragma unroll
            for (int j=0;j<8;++j) t[j] = (__bf16)p[j];
          } else {
            #pragma unroll
            for (int j=0;j<8;++j) t[j] = (__bf16)0.f;
          }
        } else {
          const float* p = recB + (c-1)*32 + kg8;
          #pragma unroll
          for (int j=0;j<8;++j) t[j] = (__bf16)p[j];
        }
      } else {
        const float* p = (c<8) ? (Wih12 + ((size_t)(l-1)*4*Hsz + R)*Hsz + c*32 + kg8)
                               : (recB + (c-8)*32 + kg8);
        #pragma unroll
        for (int j=0;j<8;++j) t[j] = (__bf16)p[j];
      }
      w[c] = t;
    }
  }

  float cst0[8], cst1[8];
  #pragma unroll
  for (int i=0;i<8;++i){ cst0[i]=0.f; cst1[i]=0.f; }

  unsigned int* myflag = flags + ((l*NG+g)*NBT + nb);
  auto slotp = [&](int ll, int s){ return hb + ((size_t)ll*PD + (s&(PD-1)))*Bsz*Hsz; };

  // ---- prologue: zero hrc (h(-1)=0); stage input(0) for both halves ----
  {
    u32x4 z = {0,0,0,0};
    #pragma unroll
    for (int j=0;j<4;++j) *(u32x4*)(smem + tid*64 + j*16) = z;   // 32K hrc0+hrc1
  }
  if constexpr (L0){
    *(uint64_t*)(ain0 + tid*8) = 0;   // zero ain0+ain1 (4KB), incl. k>=16 pad
    __syncthreads();
    float xa = xin[((size_t)(b0 +      sr)*Tsz + 0)*Fsz + sq];
    float xb = xin[((size_t)(b0 + HR + sr)*Tsz + 0)*Fsz + sq];
    *(__bf16*)(ain0 + sr*64 + sq*2) = (__bf16)xa;
    *(__bf16*)(ain1 + sr*64 + sq*2) = (__bf16)xb;
  } else {
    bf16x8 tmp[2];
    poll_load2(tmp, slotp(l-1,0) + (size_t)(b0 + sr)*Hsz + sq*16);
    *(bf16x8*)(ain0 + sr*512 + ((sq*32)    ^ skey)) = tmp[0];
    *(bf16x8*)(ain0 + sr*512 + ((sq*32+16) ^ skey)) = tmp[1];
    poll_load2(tmp, slotp(l-1,0) + (size_t)(b0 + HR + sr)*Hsz + sq*16);
    *(bf16x8*)(ain1 + sr*512 + ((sq*32)    ^ skey)) = tmp[0];
    *(bf16x8*)(ain1 + sr*512 + ((sq*32+16) ^ skey)) = tmp[1];
  }
  __syncthreads();

  bf16x8 hrvA[2], hrvB[2], hivA[2], hivB[2];
  uint32_t xvA=0, xvB=0;

  for (int t=0; t<Tsz; ++t){
    // lazy WAR guard (down-layer overrun), every 4 steps, off critical path
    if (l < 2 && (t & 3) == 0 && t >= 4 && tid < 8)
      wait_flag(flags + (((l+1)*NG + tid)*NBT + nb), t-3);

    HALF_ITER(t, t,   0,  HR, hrc0, ain0, ht0, cst0, hrvA, hivA, xvA, hrvB, hivB, xvB);
    HALF_ITER(t, t+1, HR, 0,  hrc1, ain1, ht1, cst1, hrvB, hivB, xvB, hrvA, hivA, xvA);

    if (tid==0) st_sc01_b32(myflag, (uint32_t)(t+1));
  }
}

__global__ __launch_bounds__(512, 2) void lstm_persist(
    const float* __restrict__ xin,
    const float* __restrict__ Wih0,
    const float* __restrict__ Wih12,
    const float* __restrict__ Whh,
    const float* __restrict__ bih,
    const float* __restrict__ bhh,
    __bf16* __restrict__ hb,
    unsigned int* __restrict__ flags)
{
  __shared__ __align__(16) char smem[SMEM_B];   // 84 KiB -> 1 block/CU
  const int bid = blockIdx.x;
  const int l   = bid >> 6;
  const int g   = (bid >> 3) & 7;
  const int nb  = bid & 7;
  const int tid = threadIdx.x;
  if (l == 0)
    lstm_body<true >(l,g,nb,tid, xin,Wih0,Wih12,Whh,bih,bhh, hb,flags, smem);
  else
    lstm_body<false>(l,g,nb,tid, xin,Wih0,Wih12,Whh,bih,bhh, hb,flags, smem);
}

// Pre-fill all h slots with NaN poison + zero flags (replay-safe init)
__global__ void init_ws(uint32_t* __restrict__ hb32, uint32_t* __restrict__ flags)
{
  size_t i = (size_t)blockIdx.x*blockDim.x + threadIdx.x;
  size_t n = (HBUF_ELEMS*2)/16;
  if (i < n){
    u32x4 v = {POISON, POISON, POISON, POISON};
    *(u32x4*)(hb32 + i*4) = v;
  }
  if (i < NFLAGS) flags[i] = 0;
}

__global__ void fc_kernel(const __bf16* __restrict__ hb,
                          const float* __restrict__ fcW,
                          const float* __restrict__ fcb,
                          float* __restrict__ out)
{
  __shared__ float hs[Hsz];
  int b = blockIdx.x;
  const __bf16* hp = hb + ((size_t)(2*PD + ((Tsz-1)&(PD-1))))*Bsz*Hsz + (size_t)b*Hsz;
  for (int i = threadIdx.x; i < Hsz; i += 64) hs[i] = (float)hp[i];
  __syncthreads();
  int o = threadIdx.x;
  if (o < HORZ) {
    float a = fcb[o];
    #pragma unroll 8
    for (int u=0; u<Hsz; ++u) a += hs[u]*fcW[o*Hsz + u];
    out[b*HORZ + o] = a;
  }
}

extern "C" void kernel_launch(void* const* d_in, const int* in_sizes, int n_in,
                              void* d_out, int out_size, void* d_ws, size_t ws_size,
                              hipStream_t stream)
{
  const float* x     = (const float*)d_in[0];
  const float* Wih0  = (const float*)d_in[1];
  const float* Wih12 = (const float*)d_in[2];
  const float* Whh   = (const float*)d_in[3];
  const float* bih   = (const float*)d_in[4];
  const float* bhh   = (const float*)d_in[5];
  const float* fcW   = (const float*)d_in[6];
  const float* fcb   = (const float*)d_in[7];

  __bf16* hb = (__bf16*)d_ws;
  unsigned int* flags = (unsigned int*)((char*)d_ws + HBUF_ELEMS*2);

  size_t nchunk = (HBUF_ELEMS*2)/16;
  int ib = (int)((nchunk + 255) / 256);
  hipLaunchKernelGGL(init_ws, dim3(ib), dim3(256), 0, stream, (uint32_t*)hb, flags);

  hipLaunchKernelGGL(lstm_persist, dim3(3*NG*NBT), dim3(512), 0, stream,
                     x, Wih0, Wih12, Whh, bih, bhh, hb, flags);
  hipLaunchKernelGGL(fc_kernel, dim3(Bsz), dim3(64), 0, stream, hb, fcW, fcb, (float*)d_out);
}